// Round 5
// baseline (240.899 us; speedup 1.0000x reference)
//
#include <hip/hip_runtime.h>
#include <hip/hip_bf16.h>

#define TSEQ 2048
#define NB 4
#define NH 12
#define CDIM 768

typedef short bf16x8 __attribute__((ext_vector_type(8)));
typedef float f32x4 __attribute__((ext_vector_type(4)));
typedef float f32x16 __attribute__((ext_vector_type(16)));

__device__ __forceinline__ short f2bf(float f) {
  union { float f; unsigned u; } x; x.f = f;
  unsigned r = x.u + 0x7fffu + ((x.u >> 16) & 1u);  // RNE
  return (short)(r >> 16);
}

__device__ __forceinline__ float fexp2(float x) {
  float r; asm("v_exp_f32 %0, %1" : "=v"(r) : "v"(x)); return r;
}

__device__ __forceinline__ void gload_lds16(const void* g, void* lds) {
  __builtin_amdgcn_global_load_lds(
      (const __attribute__((address_space(1))) void*)g,
      (__attribute__((address_space(3))) void*)lds, 16, 0, 0);
}

// fused fp32->bf16 cast for x, w_attn, w_proj
__global__ __launch_bounds__(256) void cast3_kernel(
    const float* __restrict__ x, const float* __restrict__ wa,
    const float* __restrict__ wp, short* __restrict__ xb,
    short* __restrict__ wab, short* __restrict__ wpb,
    int n0, int n1, int n2) {
  int i = blockIdx.x * 256 + threadIdx.x;
  const int total = n0 + n1 + n2;
  const int stride = gridDim.x * 256;
  for (; i < total; i += stride) {
    const float* src; short* dst; int j = i;
    if (j < n0)            { src = x;  dst = xb; }
    else if (j < n0 + n1)  { j -= n0; src = wa; dst = wab; }
    else                   { j -= n0 + n1; src = wp; dst = wpb; }
    float4 v = reinterpret_cast<const float4*>(src)[j];
    reinterpret_cast<short4*>(dst)[j] =
        make_short4(f2bf(v.x), f2bf(v.y), f2bf(v.z), f2bf(v.w));
  }
}

// C = A[M,K] * B[N,K]^T + bias. 128x128 tile, BK=32, dbuf LDS, 1 barrier/step.
// MODE 0: fp32 -> C0. MODE 2 (qkv, N=2304): [0,768)->K bf16; [768,1536)->Q bf16
// scaled 0.25*log2(e); [1536,2304)->V^T bf16 at C2[((b*12+h)*64+d)*2048+t].
template<int MODE>
__global__ __launch_bounds__(256) void gemm_bt_kernel(
    const short* __restrict__ A, const short* __restrict__ B,
    const float* __restrict__ bias, void* __restrict__ C0,
    void* __restrict__ C1, void* __restrict__ C2,
    int M, int N, int K) {
  __shared__ __align__(16) short As[2][4096];
  __shared__ __align__(16) short Bs[2][4096];
  const int tid = threadIdx.x;
  const int w = tid >> 6, l = tid & 63;
  const int lr = l & 15, lk = l >> 4;
  const int bm = blockIdx.x * 128, bn = blockIdx.y * 128;  // linear (no swizzle)
  const int wr = (w >> 1) * 64, wc = (w & 1) * 64;
  const int srow = tid >> 2, scol = (tid & 3) * 8;

  const short* Ag = A + (long)(bm + srow) * K + scol;
  const short* Bg = B + (long)(bn + srow) * K + scol;

  f32x4 acc[4][4] = {};
  int cur = 0;
  gload_lds16(Ag, &As[0][w * 512]);
  gload_lds16(Ag + (long)64 * K, &As[0][2048 + w * 512]);
  gload_lds16(Bg, &Bs[0][w * 512]);
  gload_lds16(Bg + (long)64 * K, &Bs[0][2048 + w * 512]);

  for (int kk = 0; kk < K; kk += 32) {
    asm volatile("s_waitcnt vmcnt(0)" ::: "memory");
    __builtin_amdgcn_s_barrier();
    asm volatile("" ::: "memory");
    if (kk + 32 < K) {
      const int nxt = cur ^ 1;
      gload_lds16(Ag + kk + 32, &As[nxt][w * 512]);
      gload_lds16(Ag + (long)64 * K + kk + 32, &As[nxt][2048 + w * 512]);
      gload_lds16(Bg + kk + 32, &Bs[nxt][w * 512]);
      gload_lds16(Bg + (long)64 * K + kk + 32, &Bs[nxt][2048 + w * 512]);
    }
    __builtin_amdgcn_sched_barrier(0);
    bf16x8 af[4], bfr[4];
#pragma unroll
    for (int m = 0; m < 4; ++m)
      af[m] = *reinterpret_cast<const bf16x8*>(&As[cur][(wr + m * 16 + lr) * 32 + lk * 8]);
#pragma unroll
    for (int n = 0; n < 4; ++n)
      bfr[n] = *reinterpret_cast<const bf16x8*>(&Bs[cur][(wc + n * 16 + lr) * 32 + lk * 8]);
    __builtin_amdgcn_s_setprio(1);
#pragma unroll
    for (int m = 0; m < 4; ++m)
#pragma unroll
      for (int n = 0; n < 4; ++n)
        acc[m][n] = __builtin_amdgcn_mfma_f32_16x16x32_bf16(af[m], bfr[n], acc[m][n], 0, 0, 0);
    __builtin_amdgcn_s_setprio(0);
    cur ^= 1;
  }

  float bv[4];
#pragma unroll
  for (int n = 0; n < 4; ++n) bv[n] = bias[bn + wc + n * 16 + lr];

  if (MODE == 0) {
#pragma unroll
    for (int m = 0; m < 4; ++m) {
      const int row0 = bm + wr + m * 16 + lk * 4;
#pragma unroll
      for (int n = 0; n < 4; ++n) {
        const int col = bn + wc + n * 16 + lr;
#pragma unroll
        for (int j = 0; j < 4; ++j)
          reinterpret_cast<float*>(C0)[(long)(row0 + j) * N + col] = acc[m][n][j] + bv[n];
      }
    }
  } else {
    const int reg_ = bn / 768;
    const int cb = bn - reg_ * 768;
    if (reg_ < 2) {
      short* dst = (short*)(reg_ ? C1 : C0);
      const float s = reg_ ? 0.36067376022224085f : 1.0f;  // Q: 0.25*log2(e)
#pragma unroll
      for (int m = 0; m < 4; ++m) {
        const int row0 = bm + wr + m * 16 + lk * 4;
#pragma unroll
        for (int n = 0; n < 4; ++n) {
          const int col = cb + wc + n * 16 + lr;
#pragma unroll
          for (int j = 0; j < 4; ++j)
            dst[(long)(row0 + j) * 768 + col] = f2bf((acc[m][n][j] + bv[n]) * s);
        }
      }
    } else {
      short* dst = (short*)C2;
#pragma unroll
      for (int m = 0; m < 4; ++m) {
        const int row0 = bm + wr + m * 16 + lk * 4;
        const int b_ = row0 >> 11, t0 = row0 & 2047;
#pragma unroll
        for (int n = 0; n < 4; ++n) {
          const int c = cb + wc + n * 16 + lr;
          short4 pk4 = make_short4(f2bf(acc[m][n][0] + bv[n]), f2bf(acc[m][n][1] + bv[n]),
                                   f2bf(acc[m][n][2] + bv[n]), f2bf(acc[m][n][3] + bv[n]));
          *reinterpret_cast<short4*>(dst + (long)((b_ * NH + (c >> 6)) * 64 + (c & 63)) * TSEQ + t0) = pk4;
        }
      }
    }
  }
}

// Flash attention v5: 32x32 fragments, ZERO LDS, zero barriers. One wave per
// block; wave owns a 32-row q-tile, paired (t, 63-t) -> uniform 65 KV-32 iters.
// Swapped QK (S^T[k][q]); softmax max in-lane + 1 shfl; P->A-frag via
// cvt_pk_bf16 + v_permlane32_swap (no LDS round-trip); row-sum via ones-MFMA;
// defer-max THR=8 (exp2 domain; rescale via rare ds_bpermute broadcast).
__global__ __launch_bounds__(64, 2) void attn_kernel(
    const short* __restrict__ Kg, const short* __restrict__ Qg,
    const short* __restrict__ Vtg, short* __restrict__ y) {
  const int l = threadIdx.x;
  const int q31 = l & 31, h8 = l >> 5;
  const int bid = blockIdx.x;
  const int swz = (bid & 7) * 192 + (bid >> 3);   // 1536 = 8 XCD * 192
  const int bh = swz >> 5, t = swz & 31;
  const int b = bh / NH, h = bh % NH;
  const short* Kbase = Kg + (long)b * TSEQ * CDIM + h * 64;
  const short* Qbase = Qg + (long)b * TSEQ * CDIM + h * 64;
  const short* Vbase = Vtg + (long)bh * 64 * TSEQ;
  const short ONE = 0x3F80;
  const bf16x8 ones = {ONE, ONE, ONE, ONE, ONE, ONE, ONE, ONE};

#pragma unroll 1
  for (int pp = 0; pp < 2; ++pp) {
    const int qt = pp ? (63 - t) : t;
    bf16x8 qf[4];
#pragma unroll
    for (int f = 0; f < 4; ++f)
      qf[f] = *reinterpret_cast<const bf16x8*>(
          Qbase + (long)(qt * 32 + q31) * CDIM + f * 16 + h8 * 8);

    f32x16 o0 = {}, o1 = {}, o5 = {};
    float m = -1e30f;

    bf16x8 ka[4], vv[4];
#pragma unroll
    for (int f = 0; f < 4; ++f)
      ka[f] = *reinterpret_cast<const bf16x8*>(
          Kbase + (long)q31 * CDIM + f * 16 + h8 * 8);
#pragma unroll
    for (int c = 0; c < 2; ++c)
#pragma unroll
      for (int s = 0; s < 2; ++s)
        vv[c * 2 + s] = *reinterpret_cast<const bf16x8*>(
            Vbase + (long)(c * 32 + q31) * TSEQ + s * 16 + h8 * 8);

#pragma unroll 1
    for (int kt = 0; kt <= qt; ++kt) {
      bf16x8 kn[4], vn[4];
      if (kt < qt) {
        const long kr = (long)((kt + 1) * 32 + q31);
#pragma unroll
        for (int f = 0; f < 4; ++f)
          kn[f] = *reinterpret_cast<const bf16x8*>(Kbase + kr * CDIM + f * 16 + h8 * 8);
#pragma unroll
        for (int c = 0; c < 2; ++c)
#pragma unroll
          for (int s = 0; s < 2; ++s)
            vn[c * 2 + s] = *reinterpret_cast<const bf16x8*>(
                Vbase + (long)(c * 32 + q31) * TSEQ + (kt + 1) * 32 + s * 16 + h8 * 8);
      }

      // S^T[k][q] = K · Q^T  (contraction over d = 64, 4 chained MFMA)
      f32x16 sc = {};
      __builtin_amdgcn_s_setprio(1);
#pragma unroll
      for (int f = 0; f < 4; ++f)
        sc = __builtin_amdgcn_mfma_f32_32x32x16_bf16(ka[f], qf[f], sc, 0, 0, 0);
      __builtin_amdgcn_s_setprio(0);

      if (kt == qt) {  // diagonal mask: k_local > q_local
#pragma unroll
        for (int r = 0; r < 16; ++r)
          if (((r & 3) + 8 * (r >> 2) + 4 * h8) > q31) sc[r] = -1e30f;
      }

      float lm = sc[0];
#pragma unroll
      for (int r = 1; r < 16; ++r) lm = fmaxf(lm, sc[r]);
      lm = fmaxf(lm, __shfl_xor(lm, 32));

      if (__any(lm > m + 8.f)) {   // defer-max: rare rescale
        const float mn = fmaxf(m, lm);
        const float al = fexp2(m - mn);
        m = mn;
#pragma unroll
        for (int r = 0; r < 16; ++r) {
          const int qr = (r & 3) + 8 * (r >> 2) + 4 * h8;
          const float av = __uint_as_float(
              __builtin_amdgcn_ds_bpermute(qr * 4, __float_as_uint(al)));
          o0[r] *= av; o1[r] *= av; o5[r] *= av;
        }
      }

      // P = exp2(S - m); pack to bf16 dwords per k-octet
      unsigned d0[4], d1[4];
#pragma unroll
      for (int oc = 0; oc < 4; ++oc) {
        float p0 = fexp2(sc[4 * oc + 0] - m), p1 = fexp2(sc[4 * oc + 1] - m);
        float p2 = fexp2(sc[4 * oc + 2] - m), p3 = fexp2(sc[4 * oc + 3] - m);
        asm("v_cvt_pk_bf16_f32 %0, %1, %2" : "=v"(d0[oc]) : "v"(p0), "v"(p1));
        asm("v_cvt_pk_bf16_f32 %0, %1, %2" : "=v"(d1[oc]) : "v"(p2), "v"(p3));
      }

      // build PV A-frags via permlane32_swap (T12)
      bf16x8 pa[2];
#pragma unroll
      for (int s = 0; s < 2; ++s) {
        unsigned a0 = d0[2 * s], b0 = d0[2 * s + 1];
        unsigned a1 = d1[2 * s], b1 = d1[2 * s + 1];
        asm("v_permlane32_swap_b32 %0, %1" : "+v"(a0), "+v"(b0));
        asm("v_permlane32_swap_b32 %0, %1" : "+v"(a1), "+v"(b1));
        union { unsigned u[4]; bf16x8 v; } u_;
        u_.u[0] = a0; u_.u[1] = a1; u_.u[2] = b0; u_.u[3] = b1;
        pa[s] = u_.v;
      }

      __builtin_amdgcn_s_setprio(1);
#pragma unroll
      for (int s = 0; s < 2; ++s) {
        o5 = __builtin_amdgcn_mfma_f32_32x32x16_bf16(pa[s], ones, o5, 0, 0, 0);
        o0 = __builtin_amdgcn_mfma_f32_32x32x16_bf16(pa[s], vv[s], o0, 0, 0, 0);
        o1 = __builtin_amdgcn_mfma_f32_32x32x16_bf16(pa[s], vv[2 + s], o1, 0, 0, 0);
      }
      __builtin_amdgcn_s_setprio(0);

#pragma unroll
      for (int f = 0; f < 4; ++f) { ka[f] = kn[f]; vv[f] = vn[f]; }
    }

    // epilogue: normalize + store (O rows: q=(r&3)+8(r>>2)+4h8, col d=q31)
#pragma unroll
    for (int r = 0; r < 16; ++r) {
      const int qr = (r & 3) + 8 * (r >> 2) + 4 * h8;
      const float inv = 1.0f / o5[r];
      const long row = (long)(b * TSEQ + qt * 32 + qr) * CDIM + h * 64;
      y[row + q31]      = f2bf(o0[r] * inv);
      y[row + 32 + q31] = f2bf(o1[r] * inv);
    }
  }
}

extern "C" void kernel_launch(void* const* d_in, const int* in_sizes, int n_in,
                              void* d_out, int out_size, void* d_ws, size_t ws_size,
                              hipStream_t stream) {
  const float* x      = (const float*)d_in[0];
  const float* w_attn = (const float*)d_in[1];
  const float* b_attn = (const float*)d_in[2];
  const float* w_proj = (const float*)d_in[3];
  const float* b_proj = (const float*)d_in[4];
  float* out = (float*)d_out;

  char* ws = (char*)d_ws;
  short* Xb  = (short*)(ws);              // 12,582,912 B
  short* Wab = (short*)(ws + 12582912);   //  3,538,944 B
  short* Wpb = (short*)(ws + 16121856);   //  1,179,648 B
  short* Kb  = (short*)(ws + 17301504);   // 12,582,912 B
  short* Qb  = (short*)(ws + 29884416);   // 12,582,912 B
  short* VtG = (short*)(ws + 42467328);   // 12,582,912 B
  short* Yb  = (short*)(ws + 55050240);   // 12,582,912 B

  const int n0 = NB * TSEQ * CDIM / 4, n1 = 3 * CDIM * CDIM / 4, n2 = CDIM * CDIM / 4;
  cast3_kernel<<<2048, 256, 0, stream>>>(x, w_attn, w_proj, Xb, Wab, Wpb, n0, n1, n2);

  gemm_bt_kernel<2><<<dim3(64, 18), 256, 0, stream>>>(Xb, Wab, b_attn, Kb, Qb, VtG, 8192, 2304, 768);
  attn_kernel<<<1536, 64, 0, stream>>>(Kb, Qb, VtG, Yb);
  gemm_bt_kernel<0><<<dim3(64, 6), 256, 0, stream>>>(Yb, Wpb, b_proj, out, nullptr, nullptr, 8192, 768, 768);
}